// Round 19
// baseline (168.029 us; speedup 1.0000x reference)
//
#include <hip/hip_runtime.h>

// ---- problem geometry ----
#define M_TOTAL 16384          // B*L
#define N_DIM   1024           // D
#define K_DIM   1024
#define L_SEQ   4096
#define B_SZ    4
#define D_DIM   1024
#define CH      64             // scan chunk length (== wave row-strip)
#define NCHUNK  (L_SEQ / CH)   // 64
#define NCHAN   (B_SZ * D_DIM) // 4096

// ---- GEMM tile ----
#define BM 128
#define BN 128
#define BK 64
#define NKT (K_DIM / BK)       // 16
#define TPB 512                // 8 waves: 2M x 4N, wave tile 64x32

typedef __attribute__((ext_vector_type(8))) short v8s;
typedef __attribute__((ext_vector_type(4))) float f32x4;

#define SB0()   __builtin_amdgcn_sched_barrier(0)
#define BAR()   __builtin_amdgcn_s_barrier()
#define WAITL0() do { asm volatile("s_waitcnt lgkmcnt(0)" ::: "memory"); SB0(); } while (0)
#define WAITL4() do { asm volatile("s_waitcnt lgkmcnt(4)" ::: "memory"); SB0(); } while (0)
#define WAITV6() do { asm volatile("s_waitcnt vmcnt(6)"   ::: "memory"); SB0(); } while (0)
#define WAITV0() do { asm volatile("s_waitcnt vmcnt(0)"   ::: "memory"); SB0(); } while (0)
#define AS1 __attribute__((address_space(1)))
#define AS3 __attribute__((address_space(3)))

__device__ __forceinline__ ushort f2b(float f) {
  uint u = __float_as_uint(f);
  u += 0x7FFFu + ((u >> 16) & 1u);   // RNE (finite inputs)
  return (ushort)(u >> 16);
}
__device__ __forceinline__ float b2f(ushort u) {
  return __uint_as_float(((uint)u) << 16);
}
__device__ __forceinline__ uint cvtpk(float lo, float hi) {  // bf16(lo) | bf16(hi)<<16, HW RNE
  uint r;
  asm("v_cvt_pk_bf16_f32 %0, %1, %2" : "=v"(r) : "v"(lo), "v"(hi));
  return r;
}

__global__ void cast_w3(const float* __restrict__ s0, const float* __restrict__ s1,
                        const float* __restrict__ s2,
                        ushort* __restrict__ o0, ushort* __restrict__ o1, ushort* __restrict__ o2) {
  int i = blockIdx.x * blockDim.x + threadIdx.x;
  const float* s = (blockIdx.y == 0) ? s0 : (blockIdx.y == 1) ? s1 : s2;
  ushort* o      = (blockIdx.y == 0) ? o0 : (blockIdx.y == 1) ? o1 : o2;
  float4 v = reinterpret_cast<const float4*>(s)[i];
  ushort4 t = make_ushort4(f2b(v.x), f2b(v.y), f2b(v.z), f2b(v.w));
  reinterpret_cast<ushort4*>(o)[i] = t;
}

// gates: f = (1+e^-ip)/(2+e^-fp+e^-ip), i = 1-f, h~ = hp>=0 ? hp+0.5 : sigmoid(hp)
__device__ __forceinline__ void gates(float fp, float ip, float hp, float& a, float& v) {
  float Ef = __expf(-fp);
  float Ei = __expf(-ip);
  float r  = __builtin_amdgcn_rcpf(2.f + Ef + Ei);
  float f  = (1.f + Ei) * r;
  float i  = (1.f + Ef) * r;
  float ht = (hp >= 0.f) ? (hp + 0.5f) : __builtin_amdgcn_rcpf(1.f + __expf(-hp));
  a = f;
  v = i * ht;
}

// Fused 3-GEMM, cast-x fused into A-staging. A f32 loads issued FIRST in group 1
// (so vmcnt(6) at the z1->z2 seam retires exactly them); convert+ds_write happens
// there, under MFMA z2 cover; boundary is near-free waits + barrier.
__launch_bounds__(TPB, 2)
__global__ void gemm_fused(const float* __restrict__ Xf,
                           const ushort* __restrict__ W0, const ushort* __restrict__ W1,
                           const ushort* __restrict__ W2,
                           const float* __restrict__ bfp, const float* __restrict__ bip,
                           const float* __restrict__ bhp,
                           uint* __restrict__ Pav,
                           float* __restrict__ AggA, float* __restrict__ AggV)
{
  __shared__ ushort lds[2][4][BM * BK];   // [buf][A,Bf,Bi,Bh]  2 x 64 KiB = 128 KiB

  // bijective XCD swizzle, 1024 blocks
  const int id  = blockIdx.x;
  const int sw  = (id & 7) * 128 + (id >> 3);
  const int n0  = (sw & 7) * BN;
  const int m0  = (sw >> 3) * BM;

  const int tid  = threadIdx.x;
  const int lane = tid & 63;
  const int w    = tid >> 6;          // 0..7
  const int wr   = w >> 2;            // 0..1 : 64-row strip (== one scan chunk)
  const int wc   = w & 3;             // 0..3 : 32-col strip
  const int fr   = lane & 15, g = lane >> 4;

  // ---- swizzled ds_read offsets (halfwords): 16B slot (ks*4+g) ^ (row&7) ----
  int aoffh[4][2], boffh[2][2];
#pragma unroll
  for (int q = 0; q < 4; ++q)
#pragma unroll
    for (int ks = 0; ks < 2; ++ks) {
      int row = wr * 64 + q * 16 + fr;
      aoffh[q][ks] = row * BK + (((ks * 4 + g) ^ (row & 7)) << 3);
    }
#pragma unroll
  for (int n = 0; n < 2; ++n)
#pragma unroll
    for (int ks = 0; ks < 2; ++ks) {
      int row = wc * 32 + n * 16 + fr;
      boffh[n][ks] = row * BK + (((ks * 4 + g) ^ (row & 7)) << 3);
    }

  // ---- staging map: slots s0=tid, s1=512+tid; inverse-swizzled source column ----
  const int s0 = tid, s1 = 512 + tid;
  const int r0 = s0 >> 3, k0 = (s0 & 7) ^ (r0 & 7);
  const int r1 = s1 >> 3, k1 = (s1 & 7) ^ (r1 & 7);
  const int d0 = s0 * 8, d1 = s1 * 8;   // halfword dest offsets (linear)

  // A source: f32 x rows
  const float* pxA0 = Xf + (size_t)(m0 + r0) * K_DIM + k0 * 8;
  const float* pxA1 = Xf + (size_t)(m0 + r1) * K_DIM + k1 * 8;

  // B sources: bf16 W rows
  const ushort* gsrcB[3][2];
  gsrcB[0][0] = W0 + (size_t)(n0 + r0) * K_DIM + k0 * 8;
  gsrcB[0][1] = W0 + (size_t)(n0 + r1) * K_DIM + k1 * 8;
  gsrcB[1][0] = W1 + (size_t)(n0 + r0) * K_DIM + k0 * 8;
  gsrcB[1][1] = W1 + (size_t)(n0 + r1) * K_DIM + k1 * 8;
  gsrcB[2][0] = W2 + (size_t)(n0 + r0) * K_DIM + k0 * 8;
  gsrcB[2][1] = W2 + (size_t)(n0 + r1) * K_DIM + k1 * 8;

  auto issueB = [&](int buf, int zb, int kt, int j) {
    const ushort* s_ = gsrcB[zb][j] + kt * BK;
    __builtin_amdgcn_global_load_lds((const AS1 void*)s_,
        (AS3 void*)(&lds[buf][1 + zb][j ? d1 : d0]), 16, 0, 0);
  };

  // convert 16 f32 -> 16 bf16 and write both A slots of buffer `buf`
  auto writeA = [&](int buf, const float4& a0, const float4& a1,
                    const float4& a2, const float4& a3) {
    uint4 u0, u1;
    u0.x = cvtpk(a0.x, a0.y); u0.y = cvtpk(a0.z, a0.w);
    u0.z = cvtpk(a1.x, a1.y); u0.w = cvtpk(a1.z, a1.w);
    u1.x = cvtpk(a2.x, a2.y); u1.y = cvtpk(a2.z, a2.w);
    u1.z = cvtpk(a3.x, a3.y); u1.w = cvtpk(a3.z, a3.w);
    *reinterpret_cast<uint4*>(&lds[buf][0][d0]) = u0;
    *reinterpret_cast<uint4*>(&lds[buf][0][d1]) = u1;
  };

  f32x4 acc[3][4][2] = {};
  float4 fA0, fA1, fA2, fA3;

  // prologue: A f32 loads, then B gloads for tile 0; drain; write A; barrier
  fA0 = *reinterpret_cast<const float4*>(pxA0);
  fA1 = *reinterpret_cast<const float4*>(pxA0 + 4);
  fA2 = *reinterpret_cast<const float4*>(pxA1);
  fA3 = *reinterpret_cast<const float4*>(pxA1 + 4);
#pragma unroll
  for (int zb = 0; zb < 3; ++zb) { issueB(0, zb, 0, 0); issueB(0, zb, 0, 1); }
  WAITV0();
  writeA(0, fA0, fA1, fA2, fA3);
  WAITL0();
  BAR(); SB0();

  int cur = 0;
  for (int t = 0; t < NKT; ++t) {
    const bool pf = (t + 1 < NKT);
    const ushort* rb = &lds[cur][0][0];
    v8s aF[4][2], bA[2][2], bB[2][2];

    // ---- issue group 1: aF + bA<-B0 (12 ds_reads); A f32 loads FIRST, then B ----
#pragma unroll
    for (int q = 0; q < 4; ++q)
#pragma unroll
      for (int ks = 0; ks < 2; ++ks)
        aF[q][ks] = *reinterpret_cast<const v8s*>(rb + aoffh[q][ks]);
#pragma unroll
    for (int n = 0; n < 2; ++n)
#pragma unroll
      for (int ks = 0; ks < 2; ++ks)
        bA[n][ks] = *reinterpret_cast<const v8s*>(rb + 1 * BM * BK + boffh[n][ks]);
    SB0();
    if (pf) {
      const int ko = (t + 1) * BK;
      fA0 = *reinterpret_cast<const float4*>(pxA0 + ko);
      fA1 = *reinterpret_cast<const float4*>(pxA0 + ko + 4);
      fA2 = *reinterpret_cast<const float4*>(pxA1 + ko);
      fA3 = *reinterpret_cast<const float4*>(pxA1 + ko + 4);
      SB0();   // pin: A loads (4 vmcnt) issue before the 6 B gloads
#pragma unroll
      for (int zb = 0; zb < 3; ++zb) { issueB(cur ^ 1, zb, t + 1, 0); issueB(cur ^ 1, zb, t + 1, 1); }
    }
    SB0();
    // ---- issue group 2: bB<-B1 (4 ds_reads) ----
#pragma unroll
    for (int n = 0; n < 2; ++n)
#pragma unroll
      for (int ks = 0; ks < 2; ++ks)
        bB[n][ks] = *reinterpret_cast<const v8s*>(rb + 2 * BM * BK + boffh[n][ks]);
    SB0();
    WAITL4();   // aF + bA landed; bB in flight
    __builtin_amdgcn_s_setprio(1);
#pragma unroll
    for (int ks = 0; ks < 2; ++ks)
#pragma unroll
      for (int mi = 0; mi < 4; ++mi) {
        acc[0][mi][0] = __builtin_amdgcn_mfma_f32_16x16x32_bf16(aF[mi][ks], bA[0][ks], acc[0][mi][0], 0, 0, 0);
        acc[0][mi][1] = __builtin_amdgcn_mfma_f32_16x16x32_bf16(aF[mi][ks], bA[1][ks], acc[0][mi][1], 0, 0, 0);
      }
    __builtin_amdgcn_s_setprio(0);
    // ---- issue group 3: bA<-B2 (4 ds_reads) ----
#pragma unroll
    for (int n = 0; n < 2; ++n)
#pragma unroll
      for (int ks = 0; ks < 2; ++ks)
        bA[n][ks] = *reinterpret_cast<const v8s*>(rb + 3 * BM * BK + boffh[n][ks]);
    SB0();
    WAITL4();   // bB landed; bA(B2) in flight
    __builtin_amdgcn_s_setprio(1);
#pragma unroll
    for (int ks = 0; ks < 2; ++ks)
#pragma unroll
      for (int mi = 0; mi < 4; ++mi) {
        acc[1][mi][0] = __builtin_amdgcn_mfma_f32_16x16x32_bf16(aF[mi][ks], bB[0][ks], acc[1][mi][0], 0, 0, 0);
        acc[1][mi][1] = __builtin_amdgcn_mfma_f32_16x16x32_bf16(aF[mi][ks], bB[1][ks], acc[1][mi][1], 0, 0, 0);
      }
    __builtin_amdgcn_s_setprio(0);
    WAITL0();   // bA(B2) landed; lgkm queue now EMPTY
    // ---- z1->z2 seam: retire A f32 loads (vmcnt 6 = the 6 B gloads), write A ----
    if (pf) {
      WAITV6();
      writeA(cur ^ 1, fA0, fA1, fA2, fA3);   // 2 ds_writes retire under MFMA z2
      SB0();
    }
    __builtin_amdgcn_s_setprio(1);
#pragma unroll
    for (int ks = 0; ks < 2; ++ks)
#pragma unroll
      for (int mi = 0; mi < 4; ++mi) {
        acc[2][mi][0] = __builtin_amdgcn_mfma_f32_16x16x32_bf16(aF[mi][ks], bA[0][ks], acc[2][mi][0], 0, 0, 0);
        acc[2][mi][1] = __builtin_amdgcn_mfma_f32_16x16x32_bf16(aF[mi][ks], bA[1][ks], acc[2][mi][1], 0, 0, 0);
      }
    __builtin_amdgcn_s_setprio(0);

    // ---- tile boundary: near-free waits + barrier ----
    if (pf) {
      WAITV0();    // 6 B gloads (issued a full tile ago)
      WAITL0();    // 2 ds_writes (issued ~8 MFMA ago)
      BAR(); SB0();
      cur ^= 1;
    }
  }

  // ---- epilogue: pack (a,v) AND build per-chunk scan aggregates ----
  const int bidx = m0 >> 12;                 // batch
  const int jch  = ((m0 & 4095) >> 6) + wr;  // per-batch chunk index of this strip
#pragma unroll
  for (int ni = 0; ni < 2; ++ni) {
    const int col = n0 + wc * 32 + ni * 16 + fr;
    const float vbf = bfp[col], vbi = bip[col], vbh = bhp[col];
    float BAgg[4], VAgg[4];
#pragma unroll
    for (int mi = 0; mi < 4; ++mi) {
      const int row0 = m0 + wr * 64 + mi * 16 + g * 4;
      float RA = 1.f, RV = 0.f;
#pragma unroll
      for (int r = 0; r < 4; ++r) {
        float a, v;
        gates(acc[0][mi][ni][r] + vbf, acc[1][mi][ni][r] + vbi, acc[2][mi][ni][r] + vbh, a, v);
        Pav[(size_t)(row0 + r) * N_DIM + col] = (uint)f2b(a) | ((uint)f2b(v) << 16);
        RA *= a; RV = fmaf(a, RV, v);
      }
      // ordered combine across g (runs at rows mi*16 + g*4): 2 xor rounds
      {
        float pA = __shfl_xor(RA, 16), pV = __shfl_xor(RV, 16);
        if (((lane >> 4) & 1) == 0) { RV = fmaf(pA, RV, pV); RA = RA * pA; }
        else                        { RV = fmaf(RA, pV, RV); RA = RA * pA; }
        pA = __shfl_xor(RA, 32); pV = __shfl_xor(RV, 32);
        if (((lane >> 5) & 1) == 0) { RV = fmaf(pA, RV, pV); RA = RA * pA; }
        else                        { RV = fmaf(RA, pV, RV); RA = RA * pA; }
      }
      BAgg[mi] = RA; VAgg[mi] = RV;
    }
    // ordered fold over mi (blocks of 16 rows)
    float CA = BAgg[0], CV = VAgg[0];
#pragma unroll
    for (int mi = 1; mi < 4; ++mi) { CV = fmaf(BAgg[mi], CV, VAgg[mi]); CA *= BAgg[mi]; }
    if (g == 0) {
      const int c = bidx * D_DIM + col;
      AggA[jch * NCHAN + c] = CA;
      AggV[jch * NCHAN + c] = CV;
    }
  }
}

// pass2 (mid fused): per-thread fold of chunk aggregates -> Start, then replay.
// Fold order per channel identical to the old scan_mid -> bit-identical h.
__global__ void scan_pass2(const uint4* __restrict__ Pav4,
                           const float4* __restrict__ AggA, const float4* __restrict__ AggV,
                           float4* __restrict__ out4)
{
  int tid = blockIdx.x * blockDim.x + threadIdx.x;   // 65536
  int c4 = tid & 1023;
  int chunk = tid >> 10;                             // wave-uniform
  int b = c4 >> 8;
  int d4 = c4 & 255;
  size_t base4 = ((size_t)b * L_SEQ + (size_t)chunk * CH) * (D_DIM / 4) + d4;

  // inline combine: h = fold_{j<chunk} (A_j, V_j), starting from 0
  float4 h = make_float4(0.f, 0.f, 0.f, 0.f);
  for (int j = 0; j < chunk; ++j) {
    float4 A = AggA[(size_t)j * (NCHAN / 4) + c4];
    float4 V = AggV[(size_t)j * (NCHAN / 4) + c4];
    h.x = fmaf(A.x, h.x, V.x);
    h.y = fmaf(A.y, h.y, V.y);
    h.z = fmaf(A.z, h.z, V.z);
    h.w = fmaf(A.w, h.w, V.w);
  }

#pragma unroll 4
  for (int t = 0; t < CH; ++t) {
    size_t idx = base4 + (size_t)t * (D_DIM / 4);
    uint4 u = Pav4[idx];
    h.x = fmaf(b2f((ushort)(u.x & 0xFFFFu)), h.x, b2f((ushort)(u.x >> 16)));
    h.y = fmaf(b2f((ushort)(u.y & 0xFFFFu)), h.y, b2f((ushort)(u.y >> 16)));
    h.z = fmaf(b2f((ushort)(u.z & 0xFFFFu)), h.z, b2f((ushort)(u.z >> 16)));
    h.w = fmaf(b2f((ushort)(u.w & 0xFFFFu)), h.w, b2f((ushort)(u.w >> 16)));
    out4[idx] = h;
  }
}

extern "C" void kernel_launch(void* const* d_in, const int* in_sizes, int n_in,
                              void* d_out, int out_size, void* d_ws, size_t ws_size,
                              hipStream_t stream) {
  (void)in_sizes; (void)n_in; (void)out_size; (void)ws_size;
  const float* x  = (const float*)d_in[0];
  const float* Wf = (const float*)d_in[1];
  const float* bf = (const float*)d_in[2];
  const float* Wi = (const float*)d_in[3];
  const float* bi = (const float*)d_in[4];
  const float* Wh = (const float*)d_in[5];
  const float* bh = (const float*)d_in[6];

  // workspace (~74 MB)
  ushort* wfb = (ushort*)d_ws;                         // 2 MB each
  ushort* wib = wfb + (size_t)N_DIM * K_DIM;
  ushort* whb = wib + (size_t)N_DIM * K_DIM;
  uint*  Pav  = (uint*)(whb + (size_t)N_DIM * K_DIM);  // 67 MB packed (a,v)
  float* AggA  = (float*)(Pav + (size_t)M_TOTAL * N_DIM);
  float* AggV  = AggA + NCHAN * NCHUNK;

  cast_w3<<<dim3((N_DIM * K_DIM / 4) / 256, 3), 256, 0, stream>>>(Wf, Wi, Wh, wfb, wib, whb);

  gemm_fused<<<dim3((M_TOTAL / BM) * (N_DIM / BN)), TPB, 0, stream>>>(
      x, wfb, wib, whb, bf, bi, bh, Pav, AggA, AggV);

  scan_pass2<<<(NCHAN / 4 * NCHUNK) / 256, 256, 0, stream>>>(
      (const uint4*)Pav, (const float4*)AggA, (const float4*)AggV, (float4*)d_out);
}

// Round 20
// 161.440 us; speedup vs baseline: 1.0408x; 1.0408x over previous
//
#include <hip/hip_runtime.h>

// ---- problem geometry ----
#define M_TOTAL 16384          // B*L
#define N_DIM   1024           // D
#define K_DIM   1024
#define L_SEQ   4096
#define B_SZ    4
#define D_DIM   1024
#define CH      64             // scan chunk length (== wave row-strip)
#define NCHUNK  (L_SEQ / CH)   // 64
#define NCHAN   (B_SZ * D_DIM) // 4096

// ---- GEMM tile ----
#define BM 128
#define BN 128
#define BK 64
#define NKT (K_DIM / BK)       // 16
#define TPB 512                // 8 waves: 2M x 4N, wave tile 64x32

typedef __attribute__((ext_vector_type(8))) short v8s;
typedef __attribute__((ext_vector_type(4))) float f32x4;

#define SB0()   __builtin_amdgcn_sched_barrier(0)
#define BAR()   __builtin_amdgcn_s_barrier()
#define WAITL0() do { asm volatile("s_waitcnt lgkmcnt(0)" ::: "memory"); SB0(); } while (0)
#define WAITL4() do { asm volatile("s_waitcnt lgkmcnt(4)" ::: "memory"); SB0(); } while (0)
#define WAITV6() do { asm volatile("s_waitcnt vmcnt(6)"   ::: "memory"); SB0(); } while (0)
#define WAITV0() do { asm volatile("s_waitcnt vmcnt(0)"   ::: "memory"); SB0(); } while (0)
#define AS1 __attribute__((address_space(1)))
#define AS3 __attribute__((address_space(3)))

__device__ __forceinline__ ushort f2b(float f) {
  uint u = __float_as_uint(f);
  u += 0x7FFFu + ((u >> 16) & 1u);   // RNE (finite inputs)
  return (ushort)(u >> 16);
}
__device__ __forceinline__ float b2f(ushort u) {
  return __uint_as_float(((uint)u) << 16);
}
__device__ __forceinline__ uint cvtpk(float lo, float hi) {  // bf16(lo) | bf16(hi)<<16, HW RNE
  uint r;
  asm("v_cvt_pk_bf16_f32 %0, %1, %2" : "=v"(r) : "v"(lo), "v"(hi));
  return r;
}

__global__ void cast_w3(const float* __restrict__ s0, const float* __restrict__ s1,
                        const float* __restrict__ s2,
                        ushort* __restrict__ o0, ushort* __restrict__ o1, ushort* __restrict__ o2) {
  int i = blockIdx.x * blockDim.x + threadIdx.x;
  const float* s = (blockIdx.y == 0) ? s0 : (blockIdx.y == 1) ? s1 : s2;
  ushort* o      = (blockIdx.y == 0) ? o0 : (blockIdx.y == 1) ? o1 : o2;
  float4 v = reinterpret_cast<const float4*>(s)[i];
  ushort4 t = make_ushort4(f2b(v.x), f2b(v.y), f2b(v.z), f2b(v.w));
  reinterpret_cast<ushort4*>(o)[i] = t;
}

// gates: f = (1+e^-ip)/(2+e^-fp+e^-ip), i = 1-f, h~ = hp>=0 ? hp+0.5 : sigmoid(hp)
__device__ __forceinline__ void gates(float fp, float ip, float hp, float& a, float& v) {
  float Ef = __expf(-fp);
  float Ei = __expf(-ip);
  float r  = __builtin_amdgcn_rcpf(2.f + Ef + Ei);
  float f  = (1.f + Ei) * r;
  float i  = (1.f + Ef) * r;
  float ht = (hp >= 0.f) ? (hp + 0.5f) : __builtin_amdgcn_rcpf(1.f + __expf(-hp));
  a = f;
  v = i * ht;
}

// Fused 3-GEMM, cast-x fused into A-staging. A f32 loads issued FIRST in group 1
// (so vmcnt(6) at the z1->z2 seam retires exactly them); convert+ds_write happens
// there, under MFMA z2 cover; boundary is near-free waits + barrier.
__launch_bounds__(TPB, 2)
__global__ void gemm_fused(const float* __restrict__ Xf,
                           const ushort* __restrict__ W0, const ushort* __restrict__ W1,
                           const ushort* __restrict__ W2,
                           const float* __restrict__ bfp, const float* __restrict__ bip,
                           const float* __restrict__ bhp,
                           uint* __restrict__ Pav,
                           float* __restrict__ AggA, float* __restrict__ AggV)
{
  __shared__ ushort lds[2][4][BM * BK];   // [buf][A,Bf,Bi,Bh]  2 x 64 KiB = 128 KiB

  // bijective XCD swizzle, 1024 blocks
  const int id  = blockIdx.x;
  const int sw  = (id & 7) * 128 + (id >> 3);
  const int n0  = (sw & 7) * BN;
  const int m0  = (sw >> 3) * BM;

  const int tid  = threadIdx.x;
  const int lane = tid & 63;
  const int w    = tid >> 6;          // 0..7
  const int wr   = w >> 2;            // 0..1 : 64-row strip (== one scan chunk)
  const int wc   = w & 3;             // 0..3 : 32-col strip
  const int fr   = lane & 15, g = lane >> 4;

  // ---- swizzled ds_read offsets (halfwords): 16B slot (ks*4+g) ^ (row&7) ----
  int aoffh[4][2], boffh[2][2];
#pragma unroll
  for (int q = 0; q < 4; ++q)
#pragma unroll
    for (int ks = 0; ks < 2; ++ks) {
      int row = wr * 64 + q * 16 + fr;
      aoffh[q][ks] = row * BK + (((ks * 4 + g) ^ (row & 7)) << 3);
    }
#pragma unroll
  for (int n = 0; n < 2; ++n)
#pragma unroll
    for (int ks = 0; ks < 2; ++ks) {
      int row = wc * 32 + n * 16 + fr;
      boffh[n][ks] = row * BK + (((ks * 4 + g) ^ (row & 7)) << 3);
    }

  // ---- staging map: slots s0=tid, s1=512+tid; inverse-swizzled source column ----
  const int s0 = tid, s1 = 512 + tid;
  const int r0 = s0 >> 3, k0 = (s0 & 7) ^ (r0 & 7);
  const int r1 = s1 >> 3, k1 = (s1 & 7) ^ (r1 & 7);
  const int d0 = s0 * 8, d1 = s1 * 8;   // halfword dest offsets (linear)

  // A source: f32 x rows
  const float* pxA0 = Xf + (size_t)(m0 + r0) * K_DIM + k0 * 8;
  const float* pxA1 = Xf + (size_t)(m0 + r1) * K_DIM + k1 * 8;

  // B sources: bf16 W rows
  const ushort* gsrcB[3][2];
  gsrcB[0][0] = W0 + (size_t)(n0 + r0) * K_DIM + k0 * 8;
  gsrcB[0][1] = W0 + (size_t)(n0 + r1) * K_DIM + k1 * 8;
  gsrcB[1][0] = W1 + (size_t)(n0 + r0) * K_DIM + k0 * 8;
  gsrcB[1][1] = W1 + (size_t)(n0 + r1) * K_DIM + k1 * 8;
  gsrcB[2][0] = W2 + (size_t)(n0 + r0) * K_DIM + k0 * 8;
  gsrcB[2][1] = W2 + (size_t)(n0 + r1) * K_DIM + k1 * 8;

  auto issueB = [&](int buf, int zb, int kt, int j) {
    const ushort* s_ = gsrcB[zb][j] + kt * BK;
    __builtin_amdgcn_global_load_lds((const AS1 void*)s_,
        (AS3 void*)(&lds[buf][1 + zb][j ? d1 : d0]), 16, 0, 0);
  };

  // convert 16 f32 -> 16 bf16 and write both A slots of buffer `buf`
  auto writeA = [&](int buf, const float4& a0, const float4& a1,
                    const float4& a2, const float4& a3) {
    uint4 u0, u1;
    u0.x = cvtpk(a0.x, a0.y); u0.y = cvtpk(a0.z, a0.w);
    u0.z = cvtpk(a1.x, a1.y); u0.w = cvtpk(a1.z, a1.w);
    u1.x = cvtpk(a2.x, a2.y); u1.y = cvtpk(a2.z, a2.w);
    u1.z = cvtpk(a3.x, a3.y); u1.w = cvtpk(a3.z, a3.w);
    *reinterpret_cast<uint4*>(&lds[buf][0][d0]) = u0;
    *reinterpret_cast<uint4*>(&lds[buf][0][d1]) = u1;
  };

  f32x4 acc[3][4][2] = {};
  float4 fA0, fA1, fA2, fA3;

  // prologue: A f32 loads, then B gloads for tile 0; drain; write A; barrier
  fA0 = *reinterpret_cast<const float4*>(pxA0);
  fA1 = *reinterpret_cast<const float4*>(pxA0 + 4);
  fA2 = *reinterpret_cast<const float4*>(pxA1);
  fA3 = *reinterpret_cast<const float4*>(pxA1 + 4);
#pragma unroll
  for (int zb = 0; zb < 3; ++zb) { issueB(0, zb, 0, 0); issueB(0, zb, 0, 1); }
  WAITV0();
  writeA(0, fA0, fA1, fA2, fA3);
  WAITL0();
  BAR(); SB0();

  int cur = 0;
  for (int t = 0; t < NKT; ++t) {
    const bool pf = (t + 1 < NKT);
    const ushort* rb = &lds[cur][0][0];
    v8s aF[4][2], bA[2][2], bB[2][2];

    // ---- issue group 1: aF + bA<-B0 (12 ds_reads); A f32 loads FIRST, then B ----
#pragma unroll
    for (int q = 0; q < 4; ++q)
#pragma unroll
      for (int ks = 0; ks < 2; ++ks)
        aF[q][ks] = *reinterpret_cast<const v8s*>(rb + aoffh[q][ks]);
#pragma unroll
    for (int n = 0; n < 2; ++n)
#pragma unroll
      for (int ks = 0; ks < 2; ++ks)
        bA[n][ks] = *reinterpret_cast<const v8s*>(rb + 1 * BM * BK + boffh[n][ks]);
    SB0();
    if (pf) {
      const int ko = (t + 1) * BK;
      fA0 = *reinterpret_cast<const float4*>(pxA0 + ko);
      fA1 = *reinterpret_cast<const float4*>(pxA0 + ko + 4);
      fA2 = *reinterpret_cast<const float4*>(pxA1 + ko);
      fA3 = *reinterpret_cast<const float4*>(pxA1 + ko + 4);
      SB0();   // pin: A loads (4 vmcnt) issue before the 6 B gloads
#pragma unroll
      for (int zb = 0; zb < 3; ++zb) { issueB(cur ^ 1, zb, t + 1, 0); issueB(cur ^ 1, zb, t + 1, 1); }
    }
    SB0();
    // ---- issue group 2: bB<-B1 (4 ds_reads) ----
#pragma unroll
    for (int n = 0; n < 2; ++n)
#pragma unroll
      for (int ks = 0; ks < 2; ++ks)
        bB[n][ks] = *reinterpret_cast<const v8s*>(rb + 2 * BM * BK + boffh[n][ks]);
    SB0();
    WAITL4();   // aF + bA landed; bB in flight
    __builtin_amdgcn_s_setprio(1);
#pragma unroll
    for (int ks = 0; ks < 2; ++ks)
#pragma unroll
      for (int mi = 0; mi < 4; ++mi) {
        acc[0][mi][0] = __builtin_amdgcn_mfma_f32_16x16x32_bf16(aF[mi][ks], bA[0][ks], acc[0][mi][0], 0, 0, 0);
        acc[0][mi][1] = __builtin_amdgcn_mfma_f32_16x16x32_bf16(aF[mi][ks], bA[1][ks], acc[0][mi][1], 0, 0, 0);
      }
    __builtin_amdgcn_s_setprio(0);
    // ---- issue group 3: bA<-B2 (4 ds_reads) ----
#pragma unroll
    for (int n = 0; n < 2; ++n)
#pragma unroll
      for (int ks = 0; ks < 2; ++ks)
        bA[n][ks] = *reinterpret_cast<const v8s*>(rb + 3 * BM * BK + boffh[n][ks]);
    SB0();
    WAITL4();   // bB landed; bA(B2) in flight
    __builtin_amdgcn_s_setprio(1);
#pragma unroll
    for (int ks = 0; ks < 2; ++ks)
#pragma unroll
      for (int mi = 0; mi < 4; ++mi) {
        acc[1][mi][0] = __builtin_amdgcn_mfma_f32_16x16x32_bf16(aF[mi][ks], bB[0][ks], acc[1][mi][0], 0, 0, 0);
        acc[1][mi][1] = __builtin_amdgcn_mfma_f32_16x16x32_bf16(aF[mi][ks], bB[1][ks], acc[1][mi][1], 0, 0, 0);
      }
    __builtin_amdgcn_s_setprio(0);
    WAITL0();   // bA(B2) landed; lgkm queue now EMPTY
    // ---- z1->z2 seam: retire A f32 loads (vmcnt 6 = the 6 B gloads), write A ----
    if (pf) {
      WAITV6();
      writeA(cur ^ 1, fA0, fA1, fA2, fA3);   // 2 ds_writes retire under MFMA z2
      SB0();
    }
    __builtin_amdgcn_s_setprio(1);
#pragma unroll
    for (int ks = 0; ks < 2; ++ks)
#pragma unroll
      for (int mi = 0; mi < 4; ++mi) {
        acc[2][mi][0] = __builtin_amdgcn_mfma_f32_16x16x32_bf16(aF[mi][ks], bA[0][ks], acc[2][mi][0], 0, 0, 0);
        acc[2][mi][1] = __builtin_amdgcn_mfma_f32_16x16x32_bf16(aF[mi][ks], bA[1][ks], acc[2][mi][1], 0, 0, 0);
      }
    __builtin_amdgcn_s_setprio(0);

    // ---- tile boundary: near-free waits + barrier ----
    if (pf) {
      WAITV0();    // 6 B gloads (issued a full tile ago)
      WAITL0();    // 2 ds_writes (issued ~8 MFMA ago)
      BAR(); SB0();
      cur ^= 1;
    }
  }

  // ---- epilogue: pack (a,v) AND build per-chunk scan aggregates ----
  const int bidx = m0 >> 12;                 // batch
  const int jch  = ((m0 & 4095) >> 6) + wr;  // per-batch chunk index of this strip
#pragma unroll
  for (int ni = 0; ni < 2; ++ni) {
    const int col = n0 + wc * 32 + ni * 16 + fr;
    const float vbf = bfp[col], vbi = bip[col], vbh = bhp[col];
    float BAgg[4], VAgg[4];
#pragma unroll
    for (int mi = 0; mi < 4; ++mi) {
      const int row0 = m0 + wr * 64 + mi * 16 + g * 4;
      float RA = 1.f, RV = 0.f;
#pragma unroll
      for (int r = 0; r < 4; ++r) {
        float a, v;
        gates(acc[0][mi][ni][r] + vbf, acc[1][mi][ni][r] + vbi, acc[2][mi][ni][r] + vbh, a, v);
        Pav[(size_t)(row0 + r) * N_DIM + col] = (uint)f2b(a) | ((uint)f2b(v) << 16);
        RA *= a; RV = fmaf(a, RV, v);
      }
      // ordered combine across g (runs at rows mi*16 + g*4): 2 xor rounds
      {
        float pA = __shfl_xor(RA, 16), pV = __shfl_xor(RV, 16);
        if (((lane >> 4) & 1) == 0) { RV = fmaf(pA, RV, pV); RA = RA * pA; }
        else                        { RV = fmaf(RA, pV, RV); RA = RA * pA; }
        pA = __shfl_xor(RA, 32); pV = __shfl_xor(RV, 32);
        if (((lane >> 5) & 1) == 0) { RV = fmaf(pA, RV, pV); RA = RA * pA; }
        else                        { RV = fmaf(RA, pV, RV); RA = RA * pA; }
      }
      BAgg[mi] = RA; VAgg[mi] = RV;
    }
    // ordered fold over mi (blocks of 16 rows)
    float CA = BAgg[0], CV = VAgg[0];
#pragma unroll
    for (int mi = 1; mi < 4; ++mi) { CV = fmaf(BAgg[mi], CV, VAgg[mi]); CA *= BAgg[mi]; }
    if (g == 0) {
      const int c = bidx * D_DIM + col;
      AggA[jch * NCHAN + c] = CA;
      AggV[jch * NCHAN + c] = CV;
    }
  }
}

// mid: sequential combine across chunk aggregates, 4 channels per thread
__global__ void scan_mid(const float4* __restrict__ AggA, const float4* __restrict__ AggV,
                         float4* __restrict__ Start)
{
  int c4 = blockIdx.x * blockDim.x + threadIdx.x;   // 1024
  float4 h = make_float4(0.f, 0.f, 0.f, 0.f);
#pragma unroll
  for (int j = 0; j < NCHUNK; ++j) {
    float4 A = AggA[(size_t)j * (NCHAN / 4) + c4];
    float4 V = AggV[(size_t)j * (NCHAN / 4) + c4];
    Start[(size_t)j * (NCHAN / 4) + c4] = h;
    h.x = fmaf(A.x, h.x, V.x);
    h.y = fmaf(A.y, h.y, V.y);
    h.z = fmaf(A.z, h.z, V.z);
    h.w = fmaf(A.w, h.w, V.w);
  }
}

// pass2: replay each chunk with true carry, 4 channels per thread, float4 out
__global__ void scan_pass2(const uint4* __restrict__ Pav4,
                           const float4* __restrict__ Start, float4* __restrict__ out4)
{
  int tid = blockIdx.x * blockDim.x + threadIdx.x;   // 65536
  int c4 = tid & 1023;
  int chunk = tid >> 10;
  int b = c4 >> 8;
  int d4 = c4 & 255;
  size_t base4 = ((size_t)b * L_SEQ + (size_t)chunk * CH) * (D_DIM / 4) + d4;
  float4 h = Start[(size_t)chunk * (NCHAN / 4) + c4];
#pragma unroll 4
  for (int t = 0; t < CH; ++t) {
    size_t idx = base4 + (size_t)t * (D_DIM / 4);
    uint4 u = Pav4[idx];
    h.x = fmaf(b2f((ushort)(u.x & 0xFFFFu)), h.x, b2f((ushort)(u.x >> 16)));
    h.y = fmaf(b2f((ushort)(u.y & 0xFFFFu)), h.y, b2f((ushort)(u.y >> 16)));
    h.z = fmaf(b2f((ushort)(u.z & 0xFFFFu)), h.z, b2f((ushort)(u.z >> 16)));
    h.w = fmaf(b2f((ushort)(u.w & 0xFFFFu)), h.w, b2f((ushort)(u.w >> 16)));
    out4[idx] = h;
  }
}

extern "C" void kernel_launch(void* const* d_in, const int* in_sizes, int n_in,
                              void* d_out, int out_size, void* d_ws, size_t ws_size,
                              hipStream_t stream) {
  (void)in_sizes; (void)n_in; (void)out_size; (void)ws_size;
  const float* x  = (const float*)d_in[0];
  const float* Wf = (const float*)d_in[1];
  const float* bf = (const float*)d_in[2];
  const float* Wi = (const float*)d_in[3];
  const float* bi = (const float*)d_in[4];
  const float* Wh = (const float*)d_in[5];
  const float* bh = (const float*)d_in[6];

  // workspace (~74 MB)
  ushort* wfb = (ushort*)d_ws;                         // 2 MB each
  ushort* wib = wfb + (size_t)N_DIM * K_DIM;
  ushort* whb = wib + (size_t)N_DIM * K_DIM;
  uint*  Pav  = (uint*)(whb + (size_t)N_DIM * K_DIM);  // 67 MB packed (a,v)
  float* AggA  = (float*)(Pav + (size_t)M_TOTAL * N_DIM);
  float* AggV  = AggA + NCHAN * NCHUNK;
  float* Start = AggV + NCHAN * NCHUNK;

  cast_w3<<<dim3((N_DIM * K_DIM / 4) / 256, 3), 256, 0, stream>>>(Wf, Wi, Wh, wfb, wib, whb);

  gemm_fused<<<dim3((M_TOTAL / BM) * (N_DIM / BN)), TPB, 0, stream>>>(
      x, wfb, wib, whb, bf, bi, bh, Pav, AggA, AggV);

  scan_mid<<<(NCHAN / 4) / 256, 256, 0, stream>>>(
      (const float4*)AggA, (const float4*)AggV, (float4*)Start);
  scan_pass2<<<(NCHAN / 4 * NCHUNK) / 256, 256, 0, stream>>>(
      (const uint4*)Pav, (const float4*)Start, (float4*)d_out);
}